// Round 8
// baseline (135.404 us; speedup 1.0000x reference)
//
#include <hip/hip_runtime.h>
#include <stdint.h>
#include <math.h>

// Problem constants (fixed by the reference)
#define DDIM    20
#define SLATE   5
#define KSEL    100
#define HID     256
#define SAMPN   16384                // prefix-sample size (docs are iid)
#define NSH     8                    // atomic shards
#define SHCAP   1024                 // per-shard candidate capacity
#define RCAP    8192                 // concat/recovery capacity per slate
#define CHUNK   2048                 // rank chunk held in LDS
#define RMT     512                  // rankmerge threads
#define OUT_IDX_OFF (SLATE * KSEL * DDIM)   // 10000

// Workspace byte offsets
#define WS_PROTO   0                 // f64[100]
#define WS_PROTOF  1024              // f32[100]
#define WS_TP2     1536              // u16[5]  T10+2
#define WS_TM2     1556              // u16[5]  T10-2
#define WS_THI     1576              // u16[5]  sample rank-100 key
#define WS_SHCNT   1600              // u32[40] stride-16 (64B lines)  <- zeroed in kernel 1
#define WS_STRICT  4160              // u32[40] stride-16              <- zeroed
#define WS_CNT2    6720              // u32[5]  stride-16 (unused)     <- zeroed
#define WS_ZEND    7040              // end of zeroed region
#define WS_SKEYS   8192              // u16[5*SAMPN]                 -> 172032
#define WS_CAND    172032            // u32[5][NSH][SHCAP]           -> 335872
#define WS_CAND2   335872            // u32[5][RCAP] concat/recovery -> 499712

// ---- exact-order f64 distance: UNCHANGED from all passing rounds ----
__device__ __forceinline__ double dleaky(double x) { return x >= 0.0 ? x : 0.01 * x; }

__device__ __forceinline__ double calc_d2(const float* doc, const double* p) {
    double acc = 0.0;
#pragma unroll
    for (int i = 0; i < DDIM; ++i) {
        double d = (double)doc[i] - p[i];
        acc = fma(d, d, acc);
    }
    return acc;
}

__device__ __forceinline__ void load_doc(const float* __restrict__ docs,
                                         size_t n, float* doc) {
    const float4* dp = (const float4*)(docs + n * DDIM);
    float4 v0 = dp[0], v1 = dp[1], v2 = dp[2], v3 = dp[3], v4 = dp[4];
    doc[0] = v0.x; doc[1] = v0.y; doc[2] = v0.z; doc[3] = v0.w;
    doc[4] = v1.x; doc[5] = v1.y; doc[6] = v1.z; doc[7] = v1.w;
    doc[8] = v2.x; doc[9] = v2.y; doc[10] = v2.z; doc[11] = v2.w;
    doc[12] = v3.x; doc[13] = v3.y; doc[14] = v3.z; doc[15] = v3.w;
    doc[16] = v4.x; doc[17] = v4.y; doc[18] = v4.z; doc[19] = v4.w;
}

// Row-dot in f64, 8x-float4 load batches; FMA order i=0..255 ascending —
// bit-identical accumulation sequence to the rolled loop of all passing
// rounds. At 256 threads there is no VGPR cap (R6/R7 lesson: only applies
// to 1024-thr blocks), so the batching actually materializes.
__device__ __forceinline__ double dot256_f64(const float* __restrict__ Wrow,
                                             const double* __restrict__ h) {
    const float4* wr = (const float4*)Wrow;     // row is 1KB, 16B-aligned
    double acc = 0.0;
#pragma unroll
    for (int b = 0; b < 8; ++b) {
        float4 v[8];
#pragma unroll
        for (int u = 0; u < 8; ++u) v[u] = wr[b * 8 + u];   // 8 independent loads
#pragma unroll
        for (int u = 0; u < 8; ++u) {
            const int i = (b * 8 + u) * 4;
            acc = fma(h[i + 0], (double)v[u].x, acc);
            acc = fma(h[i + 1], (double)v[u].y, acc);
            acc = fma(h[i + 2], (double)v[u].z, acc);
            acc = fma(h[i + 3], (double)v[u].w, acc);
        }
    }
    return acc;
}

// Guard: pure function of counters — identical wherever it is evaluated.
__device__ __forceinline__ int slate_use_primary(
    const unsigned* __restrict__ shardCnt, const unsigned* __restrict__ strictSh,
    int s) {
    unsigned strictTot = 0; bool ovf = false;
    for (int sh = 0; sh < NSH; ++sh) {
        if (shardCnt[(sh * SLATE + s) * 16] > SHCAP) ovf = true;
        strictTot += strictSh[(sh * SLATE + s) * 16];
    }
    return (strictTot >= KSEL) && !ovf;
}

// ===========================================================================
// Kernel 1: redundant f64 MLP per sampling block + sample keys + zeroing.
// R4 structure (64 blocks x 256 thr — the parallelism that R5-R7's 5-block
// fused heads destroyed), with R6's dot256_f64 batched row-dots for W2/W3.
// Block 64 zeroes counters (replaces hipMemsetAsync).
// ===========================================================================
__global__ __launch_bounds__(256) void mlp_sample_kernel(
    const float* __restrict__ x0, const float* __restrict__ docs,
    const float* __restrict__ W1, const float* __restrict__ b1,
    const float* __restrict__ W2, const float* __restrict__ b2,
    const float* __restrict__ W3, const float* __restrict__ b3,
    double* __restrict__ proto, float* __restrict__ protof,
    unsigned short* __restrict__ skeys, unsigned* __restrict__ zeroBase, int N) {
    const int bid = blockIdx.x, t = threadIdx.x;
    if (bid == SAMPN / 256) {            // zeroing block: no barriers, just exit
        for (int i = t; i < 1360; i += 256) zeroBase[i] = 0u;
        return;
    }
    __shared__ double xs[DDIM];
    __shared__ double h1[HID];
    __shared__ double h2[HID];
    __shared__ double ps[SLATE * DDIM];
    if (t < DDIM) xs[t] = (double)x0[t];
    __syncthreads();
    {
        float w[DDIM];
        load_doc(W1, (size_t)t, w);      // W1 rows are 80B, 16B-aligned
        double acc = 0.0;
#pragma unroll
        for (int i = 0; i < DDIM; ++i) acc = fma(xs[i], (double)w[i], acc);
        acc += (double)b1[t];
        h1[t] = dleaky(acc);
    }
    __syncthreads();
    {
        double acc = dot256_f64(W2 + (size_t)t * HID, h1);
        acc += (double)b2[t];
        h2[t] = dleaky(acc);
    }
    __syncthreads();
    if (t < SLATE * DDIM) {
        double acc = dot256_f64(W3 + (size_t)t * HID, h2);
        acc += (double)b3[t];
        double v = dleaky(acc);
        ps[t] = v;
        if (bid == 0) { proto[t] = v; protof[t] = (float)v; }  // for later kernels
    }
    __syncthreads();
    int i = bid * 256 + t;               // exactly covers SAMPN
    if (i < SAMPN && i < N) {
        float doc[DDIM];
        load_doc(docs, (size_t)i, doc);
#pragma unroll
        for (int s = 0; s < SLATE; ++s) {
            double d2 = calc_d2(doc, ps + s * DDIM);
            skeys[s * SAMPN + i] = (unsigned short)(__float_as_uint((float)d2) >> 16);
        }
    }
}

// -------- Kernel 2: ONE dual binary search -> ranks 10 & 100 ----------------
// (R4 verbatim — 1024 thr, kw[8] = 8 VGPR live, fits the 64-VGPR cap, fast)
__global__ __launch_bounds__(1024) void select_kernel(
    const unsigned short* __restrict__ skeys,
    unsigned short* __restrict__ Tp2, unsigned short* __restrict__ Tm2,
    unsigned short* __restrict__ Thi) {
    int s = blockIdx.x, t = threadIdx.x;
    int lane = t & 63, w = t >> 6;
    __shared__ unsigned wsum[2][16];
    const unsigned* kp = (const unsigned*)(skeys + (size_t)s * SAMPN);
    unsigned kw[8];
#pragma unroll
    for (int j = 0; j < 8; ++j) kw[j] = kp[j * 1024 + t];   // coalesced

    unsigned X10 = 0, X100 = 0;
    int buf = 0;
    for (int b = 15; b >= 0; --b) {
        unsigned p10 = X10 | (1u << b), p100 = X100 | (1u << b);
        int c10 = 0, c100 = 0;
#pragma unroll
        for (int j = 0; j < 8; ++j) {
            unsigned lo = kw[j] & 0xffffu, hi = kw[j] >> 16;
            c10  += (lo < p10)  + (hi < p10);
            c100 += (lo < p100) + (hi < p100);
        }
#pragma unroll
        for (int off = 32; off; off >>= 1) {
            c10  += __shfl_down(c10, off);
            c100 += __shfl_down(c100, off);
        }
        if (lane == 0) wsum[buf][w] = (unsigned)c10 | ((unsigned)c100 << 16);
        __syncthreads();
        unsigned t10 = 0, t100 = 0;
        for (int i = 0; i < 16; ++i) {
            unsigned v = wsum[buf][i];
            t10 += v & 0xffffu; t100 += v >> 16;
        }
        if ((int)t10 < 10)   X10 = p10;
        if ((int)t100 < 100) X100 = p100;
        buf ^= 1;
    }
    if (t == 0) {
        unsigned tp = X10 + 2u; if (tp > 65535u) tp = 65535u;
        Tp2[s] = (unsigned short)tp;
        Tm2[s] = (unsigned short)(X10 >= 2u ? X10 - 2u : 0u);
        Thi[s] = (unsigned short)X100;   // >=100 docs qualify: the samples themselves
    }
}

// -------- Kernel 3: f32 bulk filter, sharded wave-aggregated atomics --------
// (verbatim from the proven rounds; HBM-bound at ~12.3us floor for 80MB)
__global__ __launch_bounds__(256) void compact1_kernel(
    const float* __restrict__ docs, const float* __restrict__ protof,
    const unsigned short* __restrict__ Tp2, const unsigned short* __restrict__ Tm2,
    unsigned* __restrict__ shardCnt, unsigned* __restrict__ strictSh,
    unsigned* __restrict__ candIdx, int N) {
    __shared__ float psf[SLATE * DDIM];
    __shared__ unsigned short ktp[SLATE], ktm[SLATE];
    int t = threadIdx.x;
    if (t < SLATE * DDIM) psf[t] = protof[t];
    if (t < SLATE) { ktp[t] = Tp2[t]; ktm[t] = Tm2[t]; }
    __syncthreads();

    int n = blockIdx.x * 256 + t;
    bool dv = n < N;               // NO early return: ballots need full wave
    int lane = t & 63;
    int sh = blockIdx.x & (NSH - 1);

    float doc[DDIM];
    if (dv) load_doc(docs, (size_t)n, doc);
    else {
#pragma unroll
        for (int i = 0; i < DDIM; ++i) doc[i] = 0.f;
    }
    float acc[SLATE] = {0.f, 0.f, 0.f, 0.f, 0.f};
#pragma unroll
    for (int i = 0; i < DDIM; ++i) {
        float dvi = doc[i];
#pragma unroll
        for (int s = 0; s < SLATE; ++s) {
            float d = dvi - psf[s * DDIM + i];
            acc[s] = fmaf(d, d, acc[s]);   // f32 FILTER only; f64 redone later
        }
    }
#pragma unroll
    for (int s = 0; s < SLATE; ++s) {
        unsigned k32 = __float_as_uint(acc[s]) >> 16;
        bool hit = dv && k32 <= (unsigned)ktp[s];
        unsigned long long ms = __ballot(dv && k32 <= (unsigned)ktm[s]);
        if (ms) {
            int ldr = __ffsll(ms) - 1;
            if (lane == ldr)
                atomicAdd(&strictSh[(sh * SLATE + s) * 16], (unsigned)__popcll(ms));
        }
        unsigned long long mh = __ballot(hit);
        if (mh) {
            int ldr = __ffsll(mh) - 1;
            unsigned base = 0;
            if (lane == ldr)
                base = atomicAdd(&shardCnt[(sh * SLATE + s) * 16], (unsigned)__popcll(mh));
            base = __shfl(base, ldr);
            if (hit) {
                unsigned pos = base + (unsigned)__popcll(mh & ((1ull << lane) - 1ull));
                if (pos < SHCAP)
                    candIdx[((size_t)(s * NSH + sh)) * SHCAP + pos] = (unsigned)n;
            }
        }
    }
}

// ===========================================================================
// Kernel 4: rankmerge — R2's one-block-per-slate global rank (passed), with
// R4's 8-way ILP unroll fixing R2's 51us serial-LDS-chain mistake. Concats
// the 8 shard lists (~610 cands), computes exact f64 d2, ranks globally by
// (d2, idx) — identical result to per-shard-top-100 + merge-by-rank (global
// rank<100 implies shard rank<100). Recovery (guard failed; never taken in
// this bench): the slate's block scans all docs with the exact f64/Thi
// filter into scratch, then ranks. Replaces rank + boundary + merge.
// ===========================================================================
template<int NOWN>
__device__ __forceinline__ void rank_select_ilp(
    const float* __restrict__ docs, const unsigned* __restrict__ lst,
    unsigned ctot, const double* ps, double* ld, unsigned* li,
    unsigned* outIx, int t) {
    double   myD2[NOWN];
    unsigned myIx[NOWN];
    unsigned myRank[NOWN];
#pragma unroll
    for (int k = 0; k < NOWN; ++k) {
        unsigned e = (unsigned)t + (unsigned)RMT * (unsigned)k;
        myD2[k] = INFINITY; myIx[k] = 0xffffffffu; myRank[k] = 0u;
        if (e < ctot) {
            unsigned idx = lst[e];
            float doc[DDIM];
            load_doc(docs, (size_t)idx, doc);
            myIx[k] = idx;
            myD2[k] = calc_d2(doc, ps);
        }
    }
    for (unsigned c0 = 0; c0 < ctot; c0 += CHUNK) {
        unsigned cn = (ctot - c0) < CHUNK ? (ctot - c0) : CHUNK;
        __syncthreads();                        // protect ld/li reuse
        for (unsigned j = t; j < cn; j += RMT) {
            unsigned idx = lst[c0 + j];
            float doc[DDIM];
            load_doc(docs, (size_t)idx, doc);
            li[j] = idx;
            ld[j] = calc_d2(doc, ps);           // canonical exact d2
        }
        __syncthreads();
        // 8-way unrolled compare loop: 8 independent LDS reads per group
        // (R4 lesson: serial per-element LDS chains are ~120cy each)
        unsigned j = 0;
        for (; j + 8 <= cn; j += 8) {
            double d0 = ld[j+0], d1 = ld[j+1], d2 = ld[j+2], d3 = ld[j+3];
            double d4 = ld[j+4], d5 = ld[j+5], d6 = ld[j+6], d7 = ld[j+7];
            unsigned i0 = li[j+0], i1 = li[j+1], i2 = li[j+2], i3 = li[j+3];
            unsigned i4 = li[j+4], i5 = li[j+5], i6 = li[j+6], i7 = li[j+7];
#pragma unroll
            for (int k = 0; k < NOWN; ++k) {
                myRank[k] += ((d0 < myD2[k]) || (d0 == myD2[k] && i0 < myIx[k]))
                           + ((d1 < myD2[k]) || (d1 == myD2[k] && i1 < myIx[k]))
                           + ((d2 < myD2[k]) || (d2 == myD2[k] && i2 < myIx[k]))
                           + ((d3 < myD2[k]) || (d3 == myD2[k] && i3 < myIx[k]))
                           + ((d4 < myD2[k]) || (d4 == myD2[k] && i4 < myIx[k]))
                           + ((d5 < myD2[k]) || (d5 == myD2[k] && i5 < myIx[k]))
                           + ((d6 < myD2[k]) || (d6 == myD2[k] && i6 < myIx[k]))
                           + ((d7 < myD2[k]) || (d7 == myD2[k] && i7 < myIx[k]));
            }
        }
        for (; j < cn; ++j) {
            double dj = ld[j]; unsigned ij = li[j];
#pragma unroll
            for (int k = 0; k < NOWN; ++k)
                myRank[k] += ((dj < myD2[k]) || (dj == myD2[k] && ij < myIx[k])) ? 1u : 0u;
        }
    }
    __syncthreads();
#pragma unroll
    for (int k = 0; k < NOWN; ++k)
        if (myRank[k] < KSEL) outIx[myRank[k]] = myIx[k];
    // invalid slots have myD2=INF -> rank >= ctot >= KSEL -> never written
}

__global__ __launch_bounds__(RMT) void rankmerge_kernel(
    const float* __restrict__ docs, const double* __restrict__ proto,
    const unsigned short* __restrict__ Thi,
    const unsigned* __restrict__ shardCnt, const unsigned* __restrict__ strictSh,
    const unsigned* __restrict__ candIdx, unsigned* __restrict__ scratch,
    float* __restrict__ out, int N) {
    const int s = blockIdx.x, t = threadIdx.x;
    __shared__ double   ps[DDIM];
    __shared__ double   ld[CHUNK];
    __shared__ unsigned li[CHUNK];
    __shared__ unsigned offs[NSH + 1];
    __shared__ unsigned outIx[KSEL];
    __shared__ unsigned ctot_s, rcnt;
    __shared__ int      prim_s;
    if (t < DDIM) ps[t] = proto[s * DDIM + t];
    if (t == 0) {
        int p = slate_use_primary(shardCnt, strictSh, s);
        prim_s = p;
        rcnt = 0u;
        if (p) {
            unsigned o = 0;
            for (int sh = 0; sh < NSH; ++sh) {
                offs[sh] = o;
                o += shardCnt[(sh * SLATE + s) * 16];   // <= SHCAP each (guard)
            }
            offs[NSH] = o;
            ctot_s = o;                                  // <= 8192 = RCAP
        }
    }
    __syncthreads();
    unsigned* lst = scratch + (size_t)s * RCAP;
    unsigned ctot;
    if (prim_s) {
        ctot = ctot_s;
        for (unsigned e = t; e < ctot; e += RMT) {       // concat 8 shard lists
            int sh = 0;
            while (e >= offs[sh + 1]) ++sh;
            lst[e] = candIdx[((size_t)(s * NSH + sh)) * SHCAP + (e - offs[sh])];
        }
    } else {
        // exact recovery scan (same f64 key + Thi threshold as always)
        unsigned kt = Thi[s];
        for (int n = t; n < N; n += RMT) {
            float doc[DDIM];
            load_doc(docs, (size_t)n, doc);
            double d2 = calc_d2(doc, ps);
            unsigned key = __float_as_uint((float)d2) >> 16;
            if (key <= kt) {
                unsigned pos = atomicAdd(&rcnt, 1u);
                if (pos < RCAP) lst[pos] = (unsigned)n;
            }
        }
        __syncthreads();
        ctot = rcnt < RCAP ? rcnt : RCAP;
    }
    __syncthreads();   // lst[] visible block-wide (same CU; pattern passed in R2)

    if (ctot <= 1u * RMT)      rank_select_ilp<1>(docs, lst, ctot, ps, ld, li, outIx, t);
    else if (ctot <= 2u * RMT) rank_select_ilp<2>(docs, lst, ctot, ps, ld, li, outIx, t);
    else if (ctot <= 4u * RMT) rank_select_ilp<4>(docs, lst, ctot, ps, ld, li, outIx, t);
    else if (ctot <= 8u * RMT) rank_select_ilp<8>(docs, lst, ctot, ps, ld, li, outIx, t);
    else                       rank_select_ilp<16>(docs, lst, ctot, ps, ld, li, outIx, t);
    __syncthreads();

    if (t < KSEL) out[(size_t)OUT_IDX_OFF + s * KSEL + t] = (float)outIx[t];
    for (int pos = t; pos < KSEL * DDIM; pos += RMT) {
        int r = pos / DDIM, c = pos % DDIM;
        out[((size_t)s * KSEL + r) * DDIM + c] = docs[(size_t)outIx[r] * DDIM + c];
    }
}

extern "C" void kernel_launch(void* const* d_in, const int* in_sizes, int n_in,
                              void* d_out, int out_size, void* d_ws, size_t ws_size,
                              hipStream_t stream) {
    const float* x0   = (const float*)d_in[0];
    const float* docs = (const float*)d_in[1];
    const float* W1   = (const float*)d_in[2];
    const float* b1   = (const float*)d_in[3];
    const float* W2   = (const float*)d_in[4];
    const float* b2   = (const float*)d_in[5];
    const float* W3   = (const float*)d_in[6];
    const float* b3   = (const float*)d_in[7];
    int N = in_sizes[1] / DDIM;   // 1,000,000

    char* ws = (char*)d_ws;
    double*         proto    = (double*)(ws + WS_PROTO);
    float*          protof   = (float*)(ws + WS_PROTOF);
    unsigned short* Tp2      = (unsigned short*)(ws + WS_TP2);
    unsigned short* Tm2      = (unsigned short*)(ws + WS_TM2);
    unsigned short* Thi      = (unsigned short*)(ws + WS_THI);
    unsigned*       shardCnt = (unsigned*)(ws + WS_SHCNT);
    unsigned*       strictSh = (unsigned*)(ws + WS_STRICT);
    unsigned short* skeys    = (unsigned short*)(ws + WS_SKEYS);
    unsigned*       candIdx  = (unsigned*)(ws + WS_CAND);
    unsigned*       scratch  = (unsigned*)(ws + WS_CAND2);
    float*          outp     = (float*)d_out;

    // 4 kernels / 3 boundaries, all at proven-fast geometry (R7 lesson:
    // boundaries cost ~2.5us, parallelism collapse costs tens of us).
    // No cooperative launch (R1), no device-scope fences (R3), no
    // hipMemsetAsync (zeroing fused into kernel 1).
    mlp_sample_kernel<<<SAMPN / 256 + 1, 256, 0, stream>>>(
        x0, docs, W1, b1, W2, b2, W3, b3, proto, protof, skeys, shardCnt, N);
    select_kernel<<<SLATE, 1024, 0, stream>>>(skeys, Tp2, Tm2, Thi);
    int nb = (N + 255) / 256;
    compact1_kernel<<<nb, 256, 0, stream>>>(docs, protof, Tp2, Tm2,
                                            shardCnt, strictSh, candIdx, N);
    rankmerge_kernel<<<SLATE, RMT, 0, stream>>>(
        docs, proto, Thi, shardCnt, strictSh, candIdx, scratch, outp, N);
}

// Round 9
// 86.251 us; speedup vs baseline: 1.5699x; 1.5699x over previous
//
#include <hip/hip_runtime.h>
#include <stdint.h>
#include <math.h>

// Problem constants (fixed by the reference)
#define DDIM    20
#define SLATE   5
#define KSEL    100
#define HID     256
#define SAMPN   16384                // prefix-sample size (docs are iid)
#define NSH     8                    // atomic shards
#define SHCAP   1024                 // per-shard candidate capacity
#define RCAP    8192                 // recovery scratch per slate (8 slices x 1024)
#define STP     128                  // shard-top stride (pad of KSEL)
#define OUT_IDX_OFF (SLATE * KSEL * DDIM)   // 10000

// Workspace byte offsets
#define WS_PROTO   0                 // f64[100]
#define WS_PROTOF  1024              // f32[100]
#define WS_TP2     1536              // u16[5]  T10+2
#define WS_TM2     1556              // u16[5]  T10-2
#define WS_THI     1576              // u16[5]  sample rank-100 key
#define WS_SHCNT   1600              // u32[40] stride-16 (64B lines)  <- zeroed in kernel 1
#define WS_STRICT  4160              // u32[40] stride-16              <- zeroed
#define WS_CNT2    6720              // u32[5]  stride-16 (unused)     <- zeroed
#define WS_ZEND    7040              // end of zeroed region
#define WS_SKEYS   8192              // u16[5*SAMPN]                 -> 172032
#define WS_CAND    172032            // u32[5][NSH][SHCAP]           -> 335872
#define WS_CAND2   335872            // u32[5][NSH][1024] recovery   -> 499712
#define WS_STD2    499712            // f64[5][NSH][STP]             -> 540672
#define WS_STIX    540672            // u32[5][NSH][STP]             -> 561152
#define WS_STLEN   561152            // u32[5][NSH]                  -> 561312

// ---- exact-order f64 distance: UNCHANGED from all passing rounds ----
__device__ __forceinline__ double dleaky(double x) { return x >= 0.0 ? x : 0.01 * x; }

__device__ __forceinline__ double calc_d2(const float* doc, const double* p) {
    double acc = 0.0;
#pragma unroll
    for (int i = 0; i < DDIM; ++i) {
        double d = (double)doc[i] - p[i];
        acc = fma(d, d, acc);
    }
    return acc;
}

__device__ __forceinline__ void load_doc(const float* __restrict__ docs,
                                         size_t n, float* doc) {
    const float4* dp = (const float4*)(docs + n * DDIM);
    float4 v0 = dp[0], v1 = dp[1], v2 = dp[2], v3 = dp[3], v4 = dp[4];
    doc[0] = v0.x; doc[1] = v0.y; doc[2] = v0.z; doc[3] = v0.w;
    doc[4] = v1.x; doc[5] = v1.y; doc[6] = v1.z; doc[7] = v1.w;
    doc[8] = v2.x; doc[9] = v2.y; doc[10] = v2.z; doc[11] = v2.w;
    doc[12] = v3.x; doc[13] = v3.y; doc[14] = v3.z; doc[15] = v3.w;
    doc[16] = v4.x; doc[17] = v4.y; doc[18] = v4.z; doc[19] = v4.w;
}

// Row-dot in f64, 8x-float4 load batches; FMA order i=0..255 ascending —
// bit-identical accumulation sequence to the rolled loop of all passing
// rounds (validated passing in R6/R8). At 256 threads there is no VGPR cap.
__device__ __forceinline__ double dot256_f64(const float* __restrict__ Wrow,
                                             const double* __restrict__ h) {
    const float4* wr = (const float4*)Wrow;     // row is 1KB, 16B-aligned
    double acc = 0.0;
#pragma unroll
    for (int b = 0; b < 8; ++b) {
        float4 v[8];
#pragma unroll
        for (int u = 0; u < 8; ++u) v[u] = wr[b * 8 + u];   // 8 independent loads
#pragma unroll
        for (int u = 0; u < 8; ++u) {
            const int i = (b * 8 + u) * 4;
            acc = fma(h[i + 0], (double)v[u].x, acc);
            acc = fma(h[i + 1], (double)v[u].y, acc);
            acc = fma(h[i + 2], (double)v[u].z, acc);
            acc = fma(h[i + 3], (double)v[u].w, acc);
        }
    }
    return acc;
}

// Guard: pure function of counters — identical wherever it is evaluated.
__device__ __forceinline__ int slate_use_primary(
    const unsigned* __restrict__ shardCnt, const unsigned* __restrict__ strictSh,
    int s) {
    unsigned strictTot = 0; bool ovf = false;
    for (int sh = 0; sh < NSH; ++sh) {
        if (shardCnt[(sh * SLATE + s) * 16] > SHCAP) ovf = true;
        strictTot += strictSh[(sh * SLATE + s) * 16];
    }
    return (strictTot >= KSEL) && !ovf;
}

// ===========================================================================
// Kernel 1: redundant f64 MLP per sampling block + sample keys + zeroing.
// R4's proven geometry (64 blocks x 256 thr), with dot256_f64 batched
// row-dots for W2/W3 (bit-identical FMA order; the only change vs R4).
// Block 64 zeroes counters (replaces hipMemsetAsync).
// ===========================================================================
__global__ __launch_bounds__(256) void mlp_sample_kernel(
    const float* __restrict__ x0, const float* __restrict__ docs,
    const float* __restrict__ W1, const float* __restrict__ b1,
    const float* __restrict__ W2, const float* __restrict__ b2,
    const float* __restrict__ W3, const float* __restrict__ b3,
    double* __restrict__ proto, float* __restrict__ protof,
    unsigned short* __restrict__ skeys, unsigned* __restrict__ zeroBase, int N) {
    const int bid = blockIdx.x, t = threadIdx.x;
    if (bid == SAMPN / 256) {            // zeroing block: no barriers, just exit
        for (int i = t; i < 1360; i += 256) zeroBase[i] = 0u;
        return;
    }
    __shared__ double xs[DDIM];
    __shared__ double h1[HID];
    __shared__ double h2[HID];
    __shared__ double ps[SLATE * DDIM];
    if (t < DDIM) xs[t] = (double)x0[t];
    __syncthreads();
    {
        float w[DDIM];
        load_doc(W1, (size_t)t, w);      // W1 rows are 80B, 16B-aligned
        double acc = 0.0;
#pragma unroll
        for (int i = 0; i < DDIM; ++i) acc = fma(xs[i], (double)w[i], acc);
        acc += (double)b1[t];
        h1[t] = dleaky(acc);
    }
    __syncthreads();
    {
        double acc = dot256_f64(W2 + (size_t)t * HID, h1);
        acc += (double)b2[t];
        h2[t] = dleaky(acc);
    }
    __syncthreads();
    if (t < SLATE * DDIM) {
        double acc = dot256_f64(W3 + (size_t)t * HID, h2);
        acc += (double)b3[t];
        double v = dleaky(acc);
        ps[t] = v;
        if (bid == 0) { proto[t] = v; protof[t] = (float)v; }  // for later kernels
    }
    __syncthreads();
    int i = bid * 256 + t;               // exactly covers SAMPN
    if (i < SAMPN && i < N) {
        float doc[DDIM];
        load_doc(docs, (size_t)i, doc);
#pragma unroll
        for (int s = 0; s < SLATE; ++s) {
            double d2 = calc_d2(doc, ps + s * DDIM);
            skeys[s * SAMPN + i] = (unsigned short)(__float_as_uint((float)d2) >> 16);
        }
    }
}

// -------- Kernel 2: ONE dual binary search -> ranks 10 & 100 (R4 verbatim) --
__global__ __launch_bounds__(1024) void select_kernel(
    const unsigned short* __restrict__ skeys,
    unsigned short* __restrict__ Tp2, unsigned short* __restrict__ Tm2,
    unsigned short* __restrict__ Thi) {
    int s = blockIdx.x, t = threadIdx.x;
    int lane = t & 63, w = t >> 6;
    __shared__ unsigned wsum[2][16];
    const unsigned* kp = (const unsigned*)(skeys + (size_t)s * SAMPN);
    unsigned kw[8];
#pragma unroll
    for (int j = 0; j < 8; ++j) kw[j] = kp[j * 1024 + t];   // coalesced

    unsigned X10 = 0, X100 = 0;
    int buf = 0;
    for (int b = 15; b >= 0; --b) {
        unsigned p10 = X10 | (1u << b), p100 = X100 | (1u << b);
        int c10 = 0, c100 = 0;
#pragma unroll
        for (int j = 0; j < 8; ++j) {
            unsigned lo = kw[j] & 0xffffu, hi = kw[j] >> 16;
            c10  += (lo < p10)  + (hi < p10);
            c100 += (lo < p100) + (hi < p100);
        }
#pragma unroll
        for (int off = 32; off; off >>= 1) {
            c10  += __shfl_down(c10, off);
            c100 += __shfl_down(c100, off);
        }
        if (lane == 0) wsum[buf][w] = (unsigned)c10 | ((unsigned)c100 << 16);
        __syncthreads();
        unsigned t10 = 0, t100 = 0;
        for (int i = 0; i < 16; ++i) {
            unsigned v = wsum[buf][i];
            t10 += v & 0xffffu; t100 += v >> 16;
        }
        if ((int)t10 < 10)   X10 = p10;
        if ((int)t100 < 100) X100 = p100;
        buf ^= 1;
    }
    if (t == 0) {
        unsigned tp = X10 + 2u; if (tp > 65535u) tp = 65535u;
        Tp2[s] = (unsigned short)tp;
        Tm2[s] = (unsigned short)(X10 >= 2u ? X10 - 2u : 0u);
        Thi[s] = (unsigned short)X100;   // >=100 docs qualify: the samples themselves
    }
}

// -------- Kernel 3: f32 bulk filter, sharded wave-aggregated atomics --------
// (verbatim from the proven rounds; HBM-bound at ~12.3us floor for 80MB)
__global__ __launch_bounds__(256) void compact1_kernel(
    const float* __restrict__ docs, const float* __restrict__ protof,
    const unsigned short* __restrict__ Tp2, const unsigned short* __restrict__ Tm2,
    unsigned* __restrict__ shardCnt, unsigned* __restrict__ strictSh,
    unsigned* __restrict__ candIdx, int N) {
    __shared__ float psf[SLATE * DDIM];
    __shared__ unsigned short ktp[SLATE], ktm[SLATE];
    int t = threadIdx.x;
    if (t < SLATE * DDIM) psf[t] = protof[t];
    if (t < SLATE) { ktp[t] = Tp2[t]; ktm[t] = Tm2[t]; }
    __syncthreads();

    int n = blockIdx.x * 256 + t;
    bool dv = n < N;               // NO early return: ballots need full wave
    int lane = t & 63;
    int sh = blockIdx.x & (NSH - 1);

    float doc[DDIM];
    if (dv) load_doc(docs, (size_t)n, doc);
    else {
#pragma unroll
        for (int i = 0; i < DDIM; ++i) doc[i] = 0.f;
    }
    float acc[SLATE] = {0.f, 0.f, 0.f, 0.f, 0.f};
#pragma unroll
    for (int i = 0; i < DDIM; ++i) {
        float dvi = doc[i];
#pragma unroll
        for (int s = 0; s < SLATE; ++s) {
            float d = dvi - psf[s * DDIM + i];
            acc[s] = fmaf(d, d, acc[s]);   // f32 FILTER only; f64 redone later
        }
    }
#pragma unroll
    for (int s = 0; s < SLATE; ++s) {
        unsigned k32 = __float_as_uint(acc[s]) >> 16;
        bool hit = dv && k32 <= (unsigned)ktp[s];
        unsigned long long ms = __ballot(dv && k32 <= (unsigned)ktm[s]);
        if (ms) {
            int ldr = __ffsll(ms) - 1;
            if (lane == ldr)
                atomicAdd(&strictSh[(sh * SLATE + s) * 16], (unsigned)__popcll(ms));
        }
        unsigned long long mh = __ballot(hit);
        if (mh) {
            int ldr = __ffsll(mh) - 1;
            unsigned base = 0;
            if (lane == ldr)
                base = atomicAdd(&shardCnt[(sh * SLATE + s) * 16], (unsigned)__popcll(mh));
            base = __shfl(base, ldr);
            if (hit) {
                unsigned pos = base + (unsigned)__popcll(mh & ((1ull << lane) - 1ull));
                if (pos < SHCAP)
                    candIdx[((size_t)(s * NSH + sh)) * SHCAP + pos] = (unsigned)n;
            }
        }
    }
}

// ===========================================================================
// Kernel 4: per-(slate,shard) exact f64 top-100 (40 blocks), with compact2's
// recovery scan folded in. 8-way unrolled rank loop (ILP over LDS latency).
// (R4 verbatim — the 64x-less-work-per-CU geometry R8 proved essential)
// ===========================================================================
__global__ __launch_bounds__(256) void rank_kernel(
    const float* __restrict__ docs, const double* __restrict__ proto,
    const unsigned short* __restrict__ Thi,
    const unsigned* __restrict__ shardCnt, const unsigned* __restrict__ strictSh,
    const unsigned* __restrict__ candIdx, unsigned* __restrict__ rscratch,
    double* __restrict__ stD2, unsigned* __restrict__ stIx,
    unsigned* __restrict__ stLen, int N) {
    const int sh = blockIdx.x, s = blockIdx.y, t = threadIdx.x;
    __shared__ double   ld[SHCAP];
    __shared__ unsigned li[SHCAP];
    __shared__ double   ps[DDIM];
    __shared__ double   outD2[KSEL];
    __shared__ unsigned outIx[KSEL];
    __shared__ unsigned c_s, rcnt;
    __shared__ int      prim_s;

    if (t < DDIM) ps[t] = proto[s * DDIM + t];
    if (t == 0) { prim_s = slate_use_primary(shardCnt, strictSh, s); rcnt = 0u; }
    __syncthreads();

    // ---- gather candidates for this (s,sh) into LDS with exact f64 d2 ----
    unsigned c;
    if (prim_s) {
        if (t == 0) {
            unsigned cc = shardCnt[(sh * SLATE + s) * 16];
            c_s = cc > SHCAP ? SHCAP : cc;          // unreachable clamp (guard)
        }
        __syncthreads();
        c = c_s;
        const unsigned* src = candIdx + ((size_t)(s * NSH + sh)) * SHCAP;
        for (unsigned i = t; i < c; i += 256) {
            unsigned idx = src[i];
            li[i] = idx;
            float doc[DDIM];
            load_doc(docs, (size_t)idx, doc);
            ld[i] = calc_d2(doc, ps);               // canonical exact d2
        }
    } else {
        // exact recovery scan over this block's doc slice
        unsigned kt = Thi[s];
        unsigned* lst = rscratch + (size_t)s * RCAP + (size_t)sh * SHCAP;
        int lo = (int)((long long)N * sh / NSH);
        int hi = (int)((long long)N * (sh + 1) / NSH);
        for (int n = lo + t; n < hi; n += 256) {
            float doc[DDIM];
            load_doc(docs, (size_t)n, doc);
            double d2 = calc_d2(doc, ps);
            unsigned key = __float_as_uint((float)d2) >> 16;
            if (key <= kt) {
                unsigned pos = atomicAdd(&rcnt, 1u);
                if (pos < SHCAP) lst[pos] = (unsigned)n;
            }
        }
        __syncthreads();
        c = rcnt < SHCAP ? rcnt : SHCAP;
        for (unsigned i = t; i < c; i += 256) {
            unsigned idx = lst[i];
            li[i] = idx;
            float doc[DDIM];
            load_doc(docs, (size_t)idx, doc);
            ld[i] = calc_d2(doc, ps);
        }
    }
    __syncthreads();

    // ---- exact local rank by (d2, idx); 8-way unrolled LDS compare loop ----
    for (unsigned e = t; e < c; e += 256) {
        double de = ld[e]; unsigned ie = li[e];
        unsigned rank = 0;
        unsigned j = 0;
        for (; j + 8 <= c; j += 8) {
            double d0 = ld[j+0], d1 = ld[j+1], d2 = ld[j+2], d3 = ld[j+3];
            double d4 = ld[j+4], d5 = ld[j+5], d6 = ld[j+6], d7 = ld[j+7];
            unsigned i0 = li[j+0], i1 = li[j+1], i2 = li[j+2], i3 = li[j+3];
            unsigned i4 = li[j+4], i5 = li[j+5], i6 = li[j+6], i7 = li[j+7];
            rank += ((d0 < de) || (d0 == de && i0 < ie))
                  + ((d1 < de) || (d1 == de && i1 < ie))
                  + ((d2 < de) || (d2 == de && i2 < ie))
                  + ((d3 < de) || (d3 == de && i3 < ie))
                  + ((d4 < de) || (d4 == de && i4 < ie))
                  + ((d5 < de) || (d5 == de && i5 < ie))
                  + ((d6 < de) || (d6 == de && i6 < ie))
                  + ((d7 < de) || (d7 == de && i7 < ie));
        }
        for (; j < c; ++j) {
            double dj = ld[j]; unsigned ij = li[j];
            rank += (dj < de) || (dj == de && ij < ie);
        }
        if (rank < KSEL) { outD2[rank] = de; outIx[rank] = ie; }
    }
    __syncthreads();

    unsigned L = c < KSEL ? c : KSEL;
    size_t base = (size_t)(s * NSH + sh) * STP;
    for (unsigned r = t; r < L; r += 256) {
        stD2[base + r] = outD2[r];
        stIx[base + r] = outIx[r];
    }
    if (t == 0) stLen[s * NSH + sh] = L;
}

// -------- Kernel 5: merge 8 sorted lists, interleaved binary searches -------
// (R4 verbatim)
__global__ __launch_bounds__(1024) void merge_kernel(
    const float* __restrict__ docs,
    const double* __restrict__ stD2, const unsigned* __restrict__ stIx,
    const unsigned* __restrict__ stLen, float* __restrict__ out) {
    int s = blockIdx.x, t = threadIdx.x;
    __shared__ double md[NSH * KSEL];
    __shared__ unsigned mi[NSH * KSEL];
    __shared__ unsigned Ls[NSH], offs[NSH + 1];
    __shared__ unsigned sel[KSEL];
    if (t < NSH) Ls[t] = stLen[s * NSH + t];
    __syncthreads();
    if (t == 0) {
        unsigned o = 0;
        for (int sh = 0; sh < NSH; ++sh) { offs[sh] = o; o += Ls[sh]; }
        offs[NSH] = o;
    }
    __syncthreads();
    for (int sh = 0; sh < NSH; ++sh) {
        unsigned L = Ls[sh];
        for (unsigned i = t; i < L; i += 1024) {
            md[sh * KSEL + i] = stD2[(size_t)(s * NSH + sh) * STP + i];
            mi[sh * KSEL + i] = stIx[(size_t)(s * NSH + sh) * STP + i];
        }
    }
    __syncthreads();

    unsigned S = offs[NSH];
    for (unsigned e = t; e < S; e += 1024) {
        // locate (shard, local pos)
        int sh = 0;
        while (e >= offs[sh + 1]) ++sh;
        unsigned i = e - offs[sh];
        double xd = md[sh * KSEL + i];
        unsigned xi = mi[sh * KSEL + i];
        // interleaved lower_bound by (d2, idx) across the 7 other lists
        unsigned lo[NSH], hi[NSH];
#pragma unroll
        for (int so = 0; so < NSH; ++so) { lo[so] = 0; hi[so] = (so == sh) ? 0u : Ls[so]; }
        bool active = true;
        while (active) {
            active = false;
            double   dj[NSH];
            unsigned ij[NSH], mid[NSH];
#pragma unroll
            for (int so = 0; so < NSH; ++so) {
                if (lo[so] < hi[so]) {
                    unsigned m = (lo[so] + hi[so]) >> 1;
                    mid[so] = m;
                    dj[so] = md[so * KSEL + m];     // independent loads, pipelined
                    ij[so] = mi[so * KSEL + m];
                }
            }
#pragma unroll
            for (int so = 0; so < NSH; ++so) {
                if (lo[so] < hi[so]) {
                    bool less = (dj[so] < xd) || (dj[so] == xd && ij[so] < xi);
                    if (less) lo[so] = mid[so] + 1; else hi[so] = mid[so];
                    if (lo[so] < hi[so]) active = true;
                }
            }
        }
        unsigned rank = i;                        // own sorted list: i smaller
#pragma unroll
        for (int so = 0; so < NSH; ++so) rank += lo[so];
        if (rank < KSEL) sel[rank] = xi;
    }
    __syncthreads();

    if (t < KSEL) out[(size_t)OUT_IDX_OFF + s * KSEL + t] = (float)sel[t];
    for (int pos = t; pos < KSEL * DDIM; pos += 1024) {
        int r = pos / DDIM, c = pos % DDIM;
        out[((size_t)s * KSEL + r) * DDIM + c] = docs[(size_t)sel[r] * DDIM + c];
    }
}

extern "C" void kernel_launch(void* const* d_in, const int* in_sizes, int n_in,
                              void* d_out, int out_size, void* d_ws, size_t ws_size,
                              hipStream_t stream) {
    const float* x0   = (const float*)d_in[0];
    const float* docs = (const float*)d_in[1];
    const float* W1   = (const float*)d_in[2];
    const float* b1   = (const float*)d_in[3];
    const float* W2   = (const float*)d_in[4];
    const float* b2   = (const float*)d_in[5];
    const float* W3   = (const float*)d_in[6];
    const float* b3   = (const float*)d_in[7];
    int N = in_sizes[1] / DDIM;   // 1,000,000

    char* ws = (char*)d_ws;
    double*         proto    = (double*)(ws + WS_PROTO);
    float*          protof   = (float*)(ws + WS_PROTOF);
    unsigned short* Tp2      = (unsigned short*)(ws + WS_TP2);
    unsigned short* Tm2      = (unsigned short*)(ws + WS_TM2);
    unsigned short* Thi      = (unsigned short*)(ws + WS_THI);
    unsigned*       shardCnt = (unsigned*)(ws + WS_SHCNT);
    unsigned*       strictSh = (unsigned*)(ws + WS_STRICT);
    unsigned short* skeys    = (unsigned short*)(ws + WS_SKEYS);
    unsigned*       candIdx  = (unsigned*)(ws + WS_CAND);
    unsigned*       rscratch = (unsigned*)(ws + WS_CAND2);
    double*         stD2     = (double*)(ws + WS_STD2);
    unsigned*       stIx     = (unsigned*)(ws + WS_STIX);
    unsigned*       stLen    = (unsigned*)(ws + WS_STLEN);
    float*          outp     = (float*)d_out;

    // R4's proven 5-kernel pipeline (92.4us best) + dot256_f64 in kernel 1.
    // Session rules baked in: no cooperative launch (R1), no device-scope
    // fences (R3), no parallelism-collapsing fusion (R7/R8), no 1024-thr
    // blocks with >48 live VGPRs (R6), zeroing fused (R0).
    mlp_sample_kernel<<<SAMPN / 256 + 1, 256, 0, stream>>>(
        x0, docs, W1, b1, W2, b2, W3, b3, proto, protof, skeys, shardCnt, N);
    select_kernel<<<SLATE, 1024, 0, stream>>>(skeys, Tp2, Tm2, Thi);
    int nb = (N + 255) / 256;
    compact1_kernel<<<nb, 256, 0, stream>>>(docs, protof, Tp2, Tm2,
                                            shardCnt, strictSh, candIdx, N);
    rank_kernel<<<dim3(NSH, SLATE), 256, 0, stream>>>(
        docs, proto, Thi, shardCnt, strictSh, candIdx, rscratch,
        stD2, stIx, stLen, N);
    merge_kernel<<<SLATE, 1024, 0, stream>>>(docs, stD2, stIx, stLen, outp);
}